// Round 2
// baseline (985.643 us; speedup 1.0000x reference)
//
#include <hip/hip_runtime.h>
#include <cstdint>
#include <cstddef>

// ---------------------------------------------------------------------------
// WaveInterference: x -> Q,K,V (Linear) -> softmax(QK^T/sqrt(512)) V -> Wo
// B=4, S=4096, H=1024.  Heavy GEMMs in bf16 MFMA (fp32 accumulate).
//
// Workspace plan (floor ~176 MB; round-1 crash was ws overflow at 310 MB):
//   slab0: xb  (bf16 x)          -> reused as Ab (attention out) later
//   4 x 2MB:   bf16 weights
//   slab1: Qb   slab2: Kb
//   slab3: Vb                    -> reused as Pb (softmax probs) after VT
//   slab4: VTb
//   Sc (per-batch 4096x4096 fp32 = 64 MB) lives in d_out (exact fit),
//   fully consumed before the final projection overwrites d_out.
// ---------------------------------------------------------------------------

typedef unsigned short ushort_t;
typedef __bf16 bf16x8 __attribute__((ext_vector_type(8)));
typedef float f32x4 __attribute__((ext_vector_type(4)));
typedef unsigned short ushort4v __attribute__((ext_vector_type(4)));

__device__ __forceinline__ ushort_t f32_to_bf16(float f) {
  union { float f; unsigned int u; } x;
  x.f = f;
  unsigned int r = x.u + 0x7FFFu + ((x.u >> 16) & 1u);  // round-to-nearest-even
  return (ushort_t)(r >> 16);
}

// async 16B global -> LDS (LDS dst must be wave-uniform base + lane*16)
__device__ __forceinline__ void gl2lds16(const ushort_t* g, ushort_t* l) {
  __builtin_amdgcn_global_load_lds(
      (__attribute__((address_space(1))) void*)(g),
      (__attribute__((address_space(3))) void*)(l),
      16, 0, 0);
}

// ---------------------------------------------------------------------------
// fp32 -> bf16, 4 elems/thread
// ---------------------------------------------------------------------------
__global__ __launch_bounds__(256) void cvt_f32_bf16(
    const float* __restrict__ in, ushort_t* __restrict__ out, int n4) {
  int i = blockIdx.x * 256 + threadIdx.x;
  if (i >= n4) return;
  float4 f = reinterpret_cast<const float4*>(in)[i];
  ushort4v o;
  o.x = f32_to_bf16(f.x);
  o.y = f32_to_bf16(f.y);
  o.z = f32_to_bf16(f.z);
  o.w = f32_to_bf16(f.w);
  reinterpret_cast<ushort4v*>(out)[i] = o;
}

// ---------------------------------------------------------------------------
// C[m,n] = alpha * sum_k A[m,k]*B[n,k] (+ bias[n]).  A:[M,K] B:[N,K] bf16
// row-major.  128x128 tile, BK=64, 4 waves (2x2), 16x16x32 bf16 MFMA,
// global_load_lds width-16 staging (m97 pattern).  M,N %128==0, K%64==0.
// ---------------------------------------------------------------------------
template <typename OutT>
__global__ __launch_bounds__(256) void gemm_bt(
    const ushort_t* __restrict__ A, const ushort_t* __restrict__ B,
    const float* __restrict__ bias, OutT* __restrict__ C,
    int M, int N, int K, float alpha) {
  __shared__ __align__(16) ushort_t As[128 * 64];
  __shared__ __align__(16) ushort_t Bs[128 * 64];

  const int tid = threadIdx.x;
  const int lane = tid & 63;
  const int wave = tid >> 6;
  const int wm = wave >> 1;  // wave row (0..1), 64 rows each
  const int wn = wave & 1;   // wave col (0..1), 64 cols each
  const int blockRow = blockIdx.y * 128;
  const int blockCol = blockIdx.x * 128;

  // staging: each wave covers 32 rows of the 128x64 tile in 4 issues of 8 rows
  const int srow = wave * 32 + (lane >> 3);
  const int scol = (lane & 7) * 8;  // bf16 elems in the 64-wide K slab
  const ushort_t* Ag = A + (size_t)(blockRow + srow) * K + scol;
  const ushort_t* Bg = B + (size_t)(blockCol + srow) * K + scol;
  ushort_t* Al = &As[srow * 64 + scol];  // = As + (wavebase + lane*16B)
  ushort_t* Bl = &Bs[srow * 64 + scol];

  const int lm = lane & 15;    // m (A frag) / n (B frag)
  const int quad = lane >> 4;  // 0..3 -> k offset quad*8

  f32x4 acc[4][4] = {};

  for (int k0 = 0; k0 < K; k0 += 64) {
#pragma unroll
    for (int j = 0; j < 4; ++j) {
      gl2lds16(Ag + (size_t)j * 8 * K + k0, Al + j * 8 * 64);
      gl2lds16(Bg + (size_t)j * 8 * K + k0, Bl + j * 8 * 64);
    }
    __syncthreads();  // compiler emits vmcnt(0) drain before barrier
#pragma unroll
    for (int kk = 0; kk < 64; kk += 32) {
      bf16x8 af[4], bfr[4];
#pragma unroll
      for (int i = 0; i < 4; ++i) {
        af[i] = *reinterpret_cast<const bf16x8*>(
            &As[(wm * 64 + i * 16 + lm) * 64 + kk + quad * 8]);
        bfr[i] = *reinterpret_cast<const bf16x8*>(
            &Bs[(wn * 64 + i * 16 + lm) * 64 + kk + quad * 8]);
      }
#pragma unroll
      for (int i = 0; i < 4; ++i)
#pragma unroll
        for (int j = 0; j < 4; ++j)
          acc[i][j] = __builtin_amdgcn_mfma_f32_16x16x32_bf16(
              af[i], bfr[j], acc[i][j], 0, 0, 0);
    }
    __syncthreads();
  }

  // epilogue: C/D layout col = lane&15 (n), row = quad*4 + reg (m)
  const int mBase = blockRow + wm * 64 + quad * 4;
  const int nBase = blockCol + wn * 64 + lm;
#pragma unroll
  for (int j = 0; j < 4; ++j) {
    const int n = nBase + j * 16;
    const float bv = bias ? bias[n] : 0.0f;
#pragma unroll
    for (int i = 0; i < 4; ++i) {
#pragma unroll
      for (int r = 0; r < 4; ++r) {
        const int m = mBase + i * 16 + r;
        float v = acc[i][j][r] * alpha + bv;
        if constexpr (sizeof(OutT) == 2)
          C[(size_t)m * N + n] = f32_to_bf16(v);
        else
          C[(size_t)m * N + n] = v;
      }
    }
  }
}

// ---------------------------------------------------------------------------
// bf16 transpose: out[c][r] = in[r][c], per-batch slab of rows*cols.
// grid (cols/32, rows/32, batches), block 256.
// ---------------------------------------------------------------------------
__global__ __launch_bounds__(256) void transpose_bf16(
    const ushort_t* __restrict__ in, ushort_t* __restrict__ out, int rows,
    int cols) {
  __shared__ ushort_t tile[32][33];
  const size_t slab = (size_t)rows * cols;
  in += (size_t)blockIdx.z * slab;
  out += (size_t)blockIdx.z * slab;
  const int c0 = blockIdx.x * 32;
  const int r0 = blockIdx.y * 32;
  const int tx = threadIdx.x & 31;
  const int ty = threadIdx.x >> 5;  // 0..7
#pragma unroll
  for (int i = ty; i < 32; i += 8)
    tile[i][tx] = in[(size_t)(r0 + i) * cols + (c0 + tx)];
  __syncthreads();
#pragma unroll
  for (int i = ty; i < 32; i += 8)
    out[(size_t)(c0 + i) * rows + (r0 + tx)] = tile[tx][i];
}

// ---------------------------------------------------------------------------
// Row softmax over 4096 columns, fp32 in -> bf16 out.  grid (rows,1,1),
// block 256; 16 values per thread in registers.
// ---------------------------------------------------------------------------
__global__ __launch_bounds__(256) void softmax_rows(
    const float* __restrict__ Sc, ushort_t* __restrict__ P) {
  const size_t base = (size_t)blockIdx.x * 4096;
  const float* row = Sc + base;
  ushort_t* prow = P + base;
  const int tid = threadIdx.x;

  float4 v[4];
#pragma unroll
  for (int i = 0; i < 4; ++i)
    v[i] = reinterpret_cast<const float4*>(row)[i * 256 + tid];

  float mx = -3.0e38f;
#pragma unroll
  for (int i = 0; i < 4; ++i)
    mx = fmaxf(mx, fmaxf(fmaxf(v[i].x, v[i].y), fmaxf(v[i].z, v[i].w)));
#pragma unroll
  for (int o = 32; o > 0; o >>= 1) mx = fmaxf(mx, __shfl_xor(mx, o, 64));

  __shared__ float redmax[4];
  __shared__ float redsum[4];
  if ((tid & 63) == 0) redmax[tid >> 6] = mx;
  __syncthreads();
  mx = fmaxf(fmaxf(redmax[0], redmax[1]), fmaxf(redmax[2], redmax[3]));

  float sum = 0.0f;
#pragma unroll
  for (int i = 0; i < 4; ++i) {
    v[i].x = __expf(v[i].x - mx);
    v[i].y = __expf(v[i].y - mx);
    v[i].z = __expf(v[i].z - mx);
    v[i].w = __expf(v[i].w - mx);
    sum += v[i].x + v[i].y + v[i].z + v[i].w;
  }
#pragma unroll
  for (int o = 32; o > 0; o >>= 1) sum += __shfl_xor(sum, o, 64);
  if ((tid & 63) == 0) redsum[tid >> 6] = sum;
  __syncthreads();
  const float inv = 1.0f / (redsum[0] + redsum[1] + redsum[2] + redsum[3]);

#pragma unroll
  for (int i = 0; i < 4; ++i) {
    ushort4v o4;
    o4.x = f32_to_bf16(v[i].x * inv);
    o4.y = f32_to_bf16(v[i].y * inv);
    o4.z = f32_to_bf16(v[i].z * inv);
    o4.w = f32_to_bf16(v[i].w * inv);
    reinterpret_cast<ushort4v*>(prow)[i * 256 + tid] = o4;
  }
}

// ---------------------------------------------------------------------------
extern "C" void kernel_launch(void* const* d_in, const int* in_sizes, int n_in,
                              void* d_out, int out_size, void* d_ws,
                              size_t ws_size, hipStream_t stream) {
  (void)in_sizes; (void)n_in; (void)out_size; (void)ws_size;

  const float* x  = (const float*)d_in[0];
  const float* Wq = (const float*)d_in[1];
  const float* bq = (const float*)d_in[2];
  const float* Wk = (const float*)d_in[3];
  const float* bk = (const float*)d_in[4];
  const float* Wv = (const float*)d_in[5];
  const float* bv = (const float*)d_in[6];
  const float* Wo = (const float*)d_in[7];
  const float* bo = (const float*)d_in[8];
  float* out = (float*)d_out;

  constexpr int BATCH = 4, S = 4096, H = 1024;
  constexpr int M = BATCH * S;                   // 16384
  constexpr size_t SZ_X = (size_t)M * H;         // 16.8M elems (33.5 MB bf16)
  constexpr size_t SZ_W = (size_t)H * H;         // 1M elems   (2 MB bf16)
  constexpr float SCALE = 0.04419417382415922f;  // 1/sqrt(512)

  // --- workspace layout: 5 slabs + 4 weight buffers = ~168 MB total ---
  uint8_t* w = (uint8_t*)d_ws;
  ushort_t* xb  = (ushort_t*)w; w += SZ_X * 2;   // slab0: xb, later Ab
  ushort_t* wqb = (ushort_t*)w; w += SZ_W * 2;
  ushort_t* wkb = (ushort_t*)w; w += SZ_W * 2;
  ushort_t* wvb = (ushort_t*)w; w += SZ_W * 2;
  ushort_t* wob = (ushort_t*)w; w += SZ_W * 2;
  ushort_t* Qb  = (ushort_t*)w; w += SZ_X * 2;   // slab1
  ushort_t* Kb  = (ushort_t*)w; w += SZ_X * 2;   // slab2
  ushort_t* Vb  = (ushort_t*)w; w += SZ_X * 2;   // slab3: Vb, later Pb
  ushort_t* VTb = (ushort_t*)w; w += SZ_X * 2;   // slab4
  ushort_t* Ab = xb;   // x dead after V projection
  ushort_t* Pb = Vb;   // V dead after transpose
  float* Sc = out;     // per-batch 4096x4096 fp32 == out_size*4 bytes exactly;
                       // fully consumed before the final projection writes out

  const dim3 blk(256);

  // fp32 -> bf16
  cvt_f32_bf16<<<dim3((unsigned)(SZ_X / 4 / 256)), blk, 0, stream>>>(x, xb, (int)(SZ_X / 4));
  cvt_f32_bf16<<<dim3((unsigned)(SZ_W / 4 / 256)), blk, 0, stream>>>(Wq, wqb, (int)(SZ_W / 4));
  cvt_f32_bf16<<<dim3((unsigned)(SZ_W / 4 / 256)), blk, 0, stream>>>(Wk, wkb, (int)(SZ_W / 4));
  cvt_f32_bf16<<<dim3((unsigned)(SZ_W / 4 / 256)), blk, 0, stream>>>(Wv, wvb, (int)(SZ_W / 4));
  cvt_f32_bf16<<<dim3((unsigned)(SZ_W / 4 / 256)), blk, 0, stream>>>(Wo, wob, (int)(SZ_W / 4));

  // projections: Q/K/V = x @ W^T + b
  gemm_bt<ushort_t><<<dim3(H / 128, M / 128), blk, 0, stream>>>(
      xb, wqb, bq, Qb, M, H, H, 1.0f);
  gemm_bt<ushort_t><<<dim3(H / 128, M / 128), blk, 0, stream>>>(
      xb, wkb, bk, Kb, M, H, H, 1.0f);
  gemm_bt<ushort_t><<<dim3(H / 128, M / 128), blk, 0, stream>>>(
      xb, wvb, bv, Vb, M, H, H, 1.0f);

  // V^T per batch: [S,H] -> [H,S]
  transpose_bf16<<<dim3(H / 32, S / 32, BATCH), blk, 0, stream>>>(Vb, VTb, S, H);

  // attention, one batch at a time (Sc reuses d_out)
  for (int b = 0; b < BATCH; ++b) {
    const ushort_t* Qp  = Qb  + (size_t)b * S * H;
    const ushort_t* Kp  = Kb  + (size_t)b * S * H;
    const ushort_t* VTp = VTb + (size_t)b * H * S;
    ushort_t* Ap = Ab + (size_t)b * S * H;
    gemm_bt<float><<<dim3(S / 128, S / 128), blk, 0, stream>>>(
        Qp, Kp, nullptr, Sc, S, S, H, SCALE);
    softmax_rows<<<dim3(S), blk, 0, stream>>>(Sc, Pb);
    gemm_bt<ushort_t><<<dim3(H / 128, S / 128), blk, 0, stream>>>(
        Pb, VTp, nullptr, Ap, S, H, S, 1.0f);
  }

  // out = attn @ Wo^T + bo (fp32 out; overwrites the Sc scratch)
  gemm_bt<float><<<dim3(H / 128, M / 128), blk, 0, stream>>>(
      Ab, wob, bo, out, M, H, H, 1.0f);
}

// Round 3
// 929.639 us; speedup vs baseline: 1.0602x; 1.0602x over previous
//
#include <hip/hip_runtime.h>
#include <cstdint>
#include <cstddef>

// ---------------------------------------------------------------------------
// WaveInterference: x -> Q,K,V (Linear) -> softmax(QK^T/sqrt(512)) V -> Wo
// B=4, S=4096, H=1024.  Heavy GEMMs in bf16 MFMA (fp32 accumulate).
//
// R2 -> R3: PV gemm was grid-starved (256 blocks, 11% occupancy, 93 us x4).
// Now split-K=4 (grid 1024 blocks); fp32 partials live in d_out (dead between
// softmax(b) and scores(b+1)); reduce4_bf16 sums them into Ab.  QKV
// projections fused into one grid.z=3 dispatch; weight converts into one.
// Workspace unchanged at ~176 MB (ws_size known < ~310 MB from R1 crash).
// ---------------------------------------------------------------------------

typedef unsigned short ushort_t;
typedef __bf16 bf16x8 __attribute__((ext_vector_type(8)));
typedef float f32x4 __attribute__((ext_vector_type(4)));
typedef unsigned short ushort4v __attribute__((ext_vector_type(4)));

struct Bias4 { const float* p[4]; };
struct Ptr4 { const float* p[4]; };

__device__ __forceinline__ ushort_t f32_to_bf16(float f) {
  union { float f; unsigned int u; } x;
  x.f = f;
  unsigned int r = x.u + 0x7FFFu + ((x.u >> 16) & 1u);  // round-to-nearest-even
  return (ushort_t)(r >> 16);
}

// async 16B global -> LDS (LDS dst must be wave-uniform base + lane*16)
__device__ __forceinline__ void gl2lds16(const ushort_t* g, ushort_t* l) {
  __builtin_amdgcn_global_load_lds(
      (__attribute__((address_space(1))) void*)(g),
      (__attribute__((address_space(3))) void*)(l),
      16, 0, 0);
}

// ---------------------------------------------------------------------------
// fp32 -> bf16, 4 elems/thread; grid.z selects among 4 (src, dst-slab) pairs
// ---------------------------------------------------------------------------
__global__ __launch_bounds__(256) void cvt_f32_bf16(
    Ptr4 srcs, ushort_t* __restrict__ out0, size_t zstride, int n4) {
  int i = blockIdx.x * 256 + threadIdx.x;
  if (i >= n4) return;
  const float* in = srcs.p[blockIdx.z & 3];
  ushort_t* out = out0 + zstride * blockIdx.z;
  float4 f = reinterpret_cast<const float4*>(in)[i];
  ushort4v o;
  o.x = f32_to_bf16(f.x);
  o.y = f32_to_bf16(f.y);
  o.z = f32_to_bf16(f.z);
  o.w = f32_to_bf16(f.w);
  reinterpret_cast<ushort4v*>(out)[i] = o;
}

// ---------------------------------------------------------------------------
// C[m,n] = alpha * sum_{k<Klen} A[m,k]*B[n,k] (+ bias[n]).  A,B bf16 with
// leading dims lda/ldb; C has leading dim ldc.  128x128 tile, BK=64, 4 waves
// (2x2), 16x16x32 bf16 MFMA, global_load_lds width-16 staging (m97 pattern).
// blockIdx.z advances A/B/C by element strides zA/zB/zC (zA=k-offset enables
// split-K) and selects bias bz.p[z&3].  M,N %128==0, Klen%64==0.
// ---------------------------------------------------------------------------
template <typename OutT>
__global__ __launch_bounds__(256) void gemm_bt(
    const ushort_t* __restrict__ A, const ushort_t* __restrict__ B,
    Bias4 bz, OutT* __restrict__ C,
    int M, int N, int Klen, int lda, int ldb, int ldc, float alpha,
    size_t zA, size_t zB, size_t zC) {
  __shared__ __align__(16) ushort_t As[128 * 64];
  __shared__ __align__(16) ushort_t Bs[128 * 64];

  A += (size_t)blockIdx.z * zA;
  B += (size_t)blockIdx.z * zB;
  C += (size_t)blockIdx.z * zC;
  const float* bias = bz.p[blockIdx.z & 3];

  const int tid = threadIdx.x;
  const int lane = tid & 63;
  const int wave = tid >> 6;
  const int wm = wave >> 1;  // wave row (0..1), 64 rows each
  const int wn = wave & 1;   // wave col (0..1), 64 cols each
  const int blockRow = blockIdx.y * 128;
  const int blockCol = blockIdx.x * 128;

  // staging: each wave covers 32 rows of the 128x64 tile in 4 issues of 8 rows
  const int srow = wave * 32 + (lane >> 3);
  const int scol = (lane & 7) * 8;  // bf16 elems in the 64-wide K slab
  const ushort_t* Ag = A + (size_t)(blockRow + srow) * lda + scol;
  const ushort_t* Bg = B + (size_t)(blockCol + srow) * ldb + scol;
  ushort_t* Al = &As[srow * 64 + scol];  // = As + (wavebase + lane*16B)
  ushort_t* Bl = &Bs[srow * 64 + scol];

  const int lm = lane & 15;    // m (A frag) / n (B frag)
  const int quad = lane >> 4;  // 0..3 -> k offset quad*8

  f32x4 acc[4][4] = {};

  for (int k0 = 0; k0 < Klen; k0 += 64) {
#pragma unroll
    for (int j = 0; j < 4; ++j) {
      gl2lds16(Ag + (size_t)j * 8 * lda + k0, Al + j * 8 * 64);
      gl2lds16(Bg + (size_t)j * 8 * ldb + k0, Bl + j * 8 * 64);
    }
    __syncthreads();  // compiler emits vmcnt(0) drain before barrier
#pragma unroll
    for (int kk = 0; kk < 64; kk += 32) {
      bf16x8 af[4], bfr[4];
#pragma unroll
      for (int i = 0; i < 4; ++i) {
        af[i] = *reinterpret_cast<const bf16x8*>(
            &As[(wm * 64 + i * 16 + lm) * 64 + kk + quad * 8]);
        bfr[i] = *reinterpret_cast<const bf16x8*>(
            &Bs[(wn * 64 + i * 16 + lm) * 64 + kk + quad * 8]);
      }
#pragma unroll
      for (int i = 0; i < 4; ++i)
#pragma unroll
        for (int j = 0; j < 4; ++j)
          acc[i][j] = __builtin_amdgcn_mfma_f32_16x16x32_bf16(
              af[i], bfr[j], acc[i][j], 0, 0, 0);
    }
    __syncthreads();
  }

  // epilogue: C/D layout col = lane&15 (n), row = quad*4 + reg (m)
  const int mBase = blockRow + wm * 64 + quad * 4;
  const int nBase = blockCol + wn * 64 + lm;
#pragma unroll
  for (int j = 0; j < 4; ++j) {
    const int n = nBase + j * 16;
    const float bv = bias ? bias[n] : 0.0f;
#pragma unroll
    for (int i = 0; i < 4; ++i) {
#pragma unroll
      for (int r = 0; r < 4; ++r) {
        const int m = mBase + i * 16 + r;
        float v = acc[i][j][r] * alpha + bv;
        if constexpr (sizeof(OutT) == 2)
          C[(size_t)m * ldc + n] = f32_to_bf16(v);
        else
          C[(size_t)m * ldc + n] = v;
      }
    }
  }
}

// ---------------------------------------------------------------------------
// reduce 4 fp32 split-K partials (each 4096x1024) -> bf16.  n4 = elems/4.
// ---------------------------------------------------------------------------
__global__ __launch_bounds__(256) void reduce4_bf16(
    const float* __restrict__ p, ushort_t* __restrict__ o, int n4) {
  int i = blockIdx.x * 256 + threadIdx.x;
  if (i >= n4) return;
  const float4* p4 = reinterpret_cast<const float4*>(p);
  float4 a = p4[i];
  float4 b = p4[i + 1048576];
  float4 c = p4[i + 2097152];
  float4 d = p4[i + 3145728];
  ushort4v u;
  u.x = f32_to_bf16(a.x + b.x + c.x + d.x);
  u.y = f32_to_bf16(a.y + b.y + c.y + d.y);
  u.z = f32_to_bf16(a.z + b.z + c.z + d.z);
  u.w = f32_to_bf16(a.w + b.w + c.w + d.w);
  reinterpret_cast<ushort4v*>(o)[i] = u;
}

// ---------------------------------------------------------------------------
// bf16 transpose: out[c][r] = in[r][c], per-batch slab of rows*cols.
// ---------------------------------------------------------------------------
__global__ __launch_bounds__(256) void transpose_bf16(
    const ushort_t* __restrict__ in, ushort_t* __restrict__ out, int rows,
    int cols) {
  __shared__ ushort_t tile[32][33];
  const size_t slab = (size_t)rows * cols;
  in += (size_t)blockIdx.z * slab;
  out += (size_t)blockIdx.z * slab;
  const int c0 = blockIdx.x * 32;
  const int r0 = blockIdx.y * 32;
  const int tx = threadIdx.x & 31;
  const int ty = threadIdx.x >> 5;  // 0..7
#pragma unroll
  for (int i = ty; i < 32; i += 8)
    tile[i][tx] = in[(size_t)(r0 + i) * cols + (c0 + tx)];
  __syncthreads();
#pragma unroll
  for (int i = ty; i < 32; i += 8)
    out[(size_t)(c0 + i) * rows + (r0 + tx)] = tile[tx][i];
}

// ---------------------------------------------------------------------------
// Row softmax over 4096 columns, fp32 in -> bf16 out.  grid (rows,1,1),
// block 256; 16 values per thread in registers.
// ---------------------------------------------------------------------------
__global__ __launch_bounds__(256) void softmax_rows(
    const float* __restrict__ Sc, ushort_t* __restrict__ P) {
  const size_t base = (size_t)blockIdx.x * 4096;
  const float* row = Sc + base;
  ushort_t* prow = P + base;
  const int tid = threadIdx.x;

  float4 v[4];
#pragma unroll
  for (int i = 0; i < 4; ++i)
    v[i] = reinterpret_cast<const float4*>(row)[i * 256 + tid];

  float mx = -3.0e38f;
#pragma unroll
  for (int i = 0; i < 4; ++i)
    mx = fmaxf(mx, fmaxf(fmaxf(v[i].x, v[i].y), fmaxf(v[i].z, v[i].w)));
#pragma unroll
  for (int o = 32; o > 0; o >>= 1) mx = fmaxf(mx, __shfl_xor(mx, o, 64));

  __shared__ float redmax[4];
  __shared__ float redsum[4];
  if ((tid & 63) == 0) redmax[tid >> 6] = mx;
  __syncthreads();
  mx = fmaxf(fmaxf(redmax[0], redmax[1]), fmaxf(redmax[2], redmax[3]));

  float sum = 0.0f;
#pragma unroll
  for (int i = 0; i < 4; ++i) {
    v[i].x = __expf(v[i].x - mx);
    v[i].y = __expf(v[i].y - mx);
    v[i].z = __expf(v[i].z - mx);
    v[i].w = __expf(v[i].w - mx);
    sum += v[i].x + v[i].y + v[i].z + v[i].w;
  }
#pragma unroll
  for (int o = 32; o > 0; o >>= 1) sum += __shfl_xor(sum, o, 64);
  if ((tid & 63) == 0) redsum[tid >> 6] = sum;
  __syncthreads();
  const float inv = 1.0f / (redsum[0] + redsum[1] + redsum[2] + redsum[3]);

#pragma unroll
  for (int i = 0; i < 4; ++i) {
    ushort4v o4;
    o4.x = f32_to_bf16(v[i].x * inv);
    o4.y = f32_to_bf16(v[i].y * inv);
    o4.z = f32_to_bf16(v[i].z * inv);
    o4.w = f32_to_bf16(v[i].w * inv);
    reinterpret_cast<ushort4v*>(prow)[i * 256 + tid] = o4;
  }
}

// ---------------------------------------------------------------------------
extern "C" void kernel_launch(void* const* d_in, const int* in_sizes, int n_in,
                              void* d_out, int out_size, void* d_ws,
                              size_t ws_size, hipStream_t stream) {
  (void)in_sizes; (void)n_in; (void)out_size; (void)ws_size;

  const float* x  = (const float*)d_in[0];
  const float* Wq = (const float*)d_in[1];
  const float* bq = (const float*)d_in[2];
  const float* Wk = (const float*)d_in[3];
  const float* bk = (const float*)d_in[4];
  const float* Wv = (const float*)d_in[5];
  const float* bv = (const float*)d_in[6];
  const float* Wo = (const float*)d_in[7];
  const float* bo = (const float*)d_in[8];
  float* out = (float*)d_out;

  constexpr int BATCH = 4, S = 4096, H = 1024;
  constexpr int M = BATCH * S;                   // 16384
  constexpr size_t SZ_X = (size_t)M * H;         // 16.8M elems (33.5 MB bf16)
  constexpr size_t SZ_W = (size_t)H * H;         // 1M elems   (2 MB bf16)
  constexpr float SCALE = 0.04419417382415922f;  // 1/sqrt(512)

  // --- workspace layout: 5 slabs + 4 weight buffers = ~176 MB total ---
  uint8_t* w = (uint8_t*)d_ws;
  ushort_t* xb  = (ushort_t*)w; w += SZ_X * 2;   // slab0: xb, later Ab
  ushort_t* wqb = (ushort_t*)w; w += SZ_W * 2;   // wq/wk/wv/wo contiguous
  ushort_t* wkb = (ushort_t*)w; w += SZ_W * 2;
  ushort_t* wvb = (ushort_t*)w; w += SZ_W * 2;
  ushort_t* wob = (ushort_t*)w; w += SZ_W * 2;
  ushort_t* Qb  = (ushort_t*)w; w += SZ_X * 2;   // slab1 (Q/K/V contiguous)
  ushort_t* Kb  = (ushort_t*)w; w += SZ_X * 2;   // slab2
  ushort_t* Vb  = (ushort_t*)w; w += SZ_X * 2;   // slab3: Vb, later Pb
  ushort_t* VTb = (ushort_t*)w; w += SZ_X * 2;   // slab4
  ushort_t* Ab = xb;   // x dead after QKV projection
  ushort_t* Pb = Vb;   // V dead after transpose
  float* Sc = out;     // d_out doubles as scores / split-K partials scratch;
                       // fully consumed before the final projection writes out
  (void)wkb; (void)wvb;

  const dim3 blk(256);
  const Bias4 nobias = {{nullptr, nullptr, nullptr, nullptr}};

  // fp32 -> bf16: x (z=0 only), then 4 weights in one grid.z=4 dispatch
  {
    Ptr4 px = {{x, nullptr, nullptr, nullptr}};
    cvt_f32_bf16<<<dim3((unsigned)(SZ_X / 4 / 256), 1, 1), blk, 0, stream>>>(
        px, xb, 0, (int)(SZ_X / 4));
    Ptr4 pw = {{Wq, Wk, Wv, Wo}};
    cvt_f32_bf16<<<dim3((unsigned)(SZ_W / 4 / 256), 1, 4), blk, 0, stream>>>(
        pw, wqb, SZ_W, (int)(SZ_W / 4));
  }

  // fused Q/K/V projections: one dispatch, grid.z picks weight/bias/output
  {
    Bias4 bqkv = {{bq, bk, bv, nullptr}};
    gemm_bt<ushort_t><<<dim3(H / 128, M / 128, 3), blk, 0, stream>>>(
        xb, wqb, bqkv, Qb, M, H, H, H, H, H, 1.0f, 0, SZ_W, SZ_X);
  }

  // V^T per batch: [S,H] -> [H,S]
  transpose_bf16<<<dim3(H / 32, S / 32, BATCH), blk, 0, stream>>>(Vb, VTb, S, H);

  // attention, one batch at a time (Sc / split-K partials reuse d_out)
  for (int b = 0; b < BATCH; ++b) {
    const ushort_t* Qp  = Qb  + (size_t)b * S * H;
    const ushort_t* Kp  = Kb  + (size_t)b * S * H;
    const ushort_t* VTp = VTb + (size_t)b * H * S;
    ushort_t* Ap = Ab + (size_t)b * S * H;
    // scores: [S,S] fp32 into d_out
    gemm_bt<float><<<dim3(S / 128, S / 128, 1), blk, 0, stream>>>(
        Qp, Kp, nobias, Sc, S, S, H, H, H, S, SCALE, 0, 0, 0);
    softmax_rows<<<dim3(S), blk, 0, stream>>>(Sc, Pb);
    // P @ V^T with split-K=4: z shifts the k-window by 1024 (zA=zB=1024),
    // each z writes its own fp32 partial (zC = S*H elems) into d_out
    gemm_bt<float><<<dim3(H / 128, S / 128, 4), blk, 0, stream>>>(
        Pb, VTp, nobias, (float*)out, S, H, 1024, S, S, H, 1.0f,
        1024, 1024, (size_t)S * H);
    reduce4_bf16<<<dim3((unsigned)(S * H / 4 / 256)), blk, 0, stream>>>(
        (const float*)out, Ap, S * H / 4);
  }

  // out = attn @ Wo^T + bo (fp32 out; overwrites the scratch in d_out)
  gemm_bt<float><<<dim3(H / 128, M / 128, 1), blk, 0, stream>>>(
      Ab, wob, {{bo, nullptr, nullptr, nullptr}}, out, M, H, H, H, H, H,
      1.0f, 0, 0, 0);
}

// Round 4
// 905.702 us; speedup vs baseline: 1.0883x; 1.0264x over previous
//
#include <hip/hip_runtime.h>
#include <cstdint>
#include <cstddef>

// ---------------------------------------------------------------------------
// WaveInterference: x -> Q,K,V (Linear) -> softmax(QK^T/sqrt(512)) V -> Wo
// B=4, S=4096, H=1024.  Heavy GEMMs in bf16 MFMA (fp32 accumulate).
//
// R3 -> R4: gemm_bt FETCH_SIZE was ~4x ideal (QKV: 399 MB vs ~106 MB).
// Cause: XCD = linear_block_id % 8 = blockIdx.x, so each XCD streamed the
// whole A matrix through its 4 MB L2.  Fix: in-kernel band swizzle — each
// XCD owns a horizontal band of NY/8 block-rows, enumerated column-major
// (A band stays L2-resident; B streamed once per XCD).
// ---------------------------------------------------------------------------

typedef unsigned short ushort_t;
typedef __bf16 bf16x8 __attribute__((ext_vector_type(8)));
typedef float f32x4 __attribute__((ext_vector_type(4)));
typedef unsigned short ushort4v __attribute__((ext_vector_type(4)));

struct Bias4 { const float* p[4]; };
struct Ptr4 { const float* p[4]; };

__device__ __forceinline__ ushort_t f32_to_bf16(float f) {
  union { float f; unsigned int u; } x;
  x.f = f;
  unsigned int r = x.u + 0x7FFFu + ((x.u >> 16) & 1u);  // round-to-nearest-even
  return (ushort_t)(r >> 16);
}

// async 16B global -> LDS (LDS dst must be wave-uniform base + lane*16)
__device__ __forceinline__ void gl2lds16(const ushort_t* g, ushort_t* l) {
  __builtin_amdgcn_global_load_lds(
      (__attribute__((address_space(1))) void*)(g),
      (__attribute__((address_space(3))) void*)(l),
      16, 0, 0);
}

// ---------------------------------------------------------------------------
// fp32 -> bf16, 4 elems/thread; grid.z selects among 4 (src, dst-slab) pairs
// ---------------------------------------------------------------------------
__global__ __launch_bounds__(256) void cvt_f32_bf16(
    Ptr4 srcs, ushort_t* __restrict__ out0, size_t zstride, int n4) {
  int i = blockIdx.x * 256 + threadIdx.x;
  if (i >= n4) return;
  const float* in = srcs.p[blockIdx.z & 3];
  ushort_t* out = out0 + zstride * blockIdx.z;
  float4 f = reinterpret_cast<const float4*>(in)[i];
  ushort4v o;
  o.x = f32_to_bf16(f.x);
  o.y = f32_to_bf16(f.y);
  o.z = f32_to_bf16(f.z);
  o.w = f32_to_bf16(f.w);
  reinterpret_cast<ushort4v*>(out)[i] = o;
}

// ---------------------------------------------------------------------------
// C[m,n] = alpha * sum_{k<Klen} A[m,k]*B[n,k] (+ bias[n]).  A,B bf16 with
// leading dims lda/ldb; C leading dim ldc.  128x128 tile, BK=64, 4 waves
// (2x2), 16x16x32 bf16 MFMA, global_load_lds width-16 staging (m97 pattern).
// blockIdx.z advances A/B/C by element strides zA/zB/zC (zA=k-offset enables
// split-K) and selects bias bz.p[z&3].  Requires gridDim.y % 8 == 0.
// ---------------------------------------------------------------------------
template <typename OutT>
__global__ __launch_bounds__(256) void gemm_bt(
    const ushort_t* __restrict__ A, const ushort_t* __restrict__ B,
    Bias4 bz, OutT* __restrict__ C,
    int M, int N, int Klen, int lda, int ldb, int ldc, float alpha,
    size_t zA, size_t zB, size_t zC) {
  __shared__ __align__(16) ushort_t As[128 * 64];
  __shared__ __align__(16) ushort_t Bs[128 * 64];

  A += (size_t)blockIdx.z * zA;
  B += (size_t)blockIdx.z * zB;
  C += (size_t)blockIdx.z * zC;
  const float* bias = bz.p[blockIdx.z & 3];

  // --- XCD band swizzle.  HW: xcd = (bx + NX*by) % 8.  Give each XCD a
  // horizontal band of NY/8 block-rows, walked column-major so the A band
  // stays L2-resident while B streams through once per XCD. ---
  const int flat = blockIdx.x + gridDim.x * blockIdx.y;
  const int bandH = gridDim.y >> 3;
  const int xcd = flat & 7;
  const int slot = flat >> 3;
  const int bxs = slot / bandH;
  const int bys = xcd * bandH + (slot - bxs * bandH);
  const int blockRow = bys * 128;
  const int blockCol = bxs * 128;

  const int tid = threadIdx.x;
  const int lane = tid & 63;
  const int wave = tid >> 6;
  const int wm = wave >> 1;  // wave row (0..1), 64 rows each
  const int wn = wave & 1;   // wave col (0..1), 64 cols each

  // staging: each wave covers 32 rows of the 128x64 tile in 4 issues of 8 rows
  const int srow = wave * 32 + (lane >> 3);
  const int scol = (lane & 7) * 8;  // bf16 elems in the 64-wide K slab
  const ushort_t* Ag = A + (size_t)(blockRow + srow) * lda + scol;
  const ushort_t* Bg = B + (size_t)(blockCol + srow) * ldb + scol;
  ushort_t* Al = &As[srow * 64 + scol];  // = As + (wavebase + lane*16B)
  ushort_t* Bl = &Bs[srow * 64 + scol];

  const int lm = lane & 15;    // m (A frag) / n (B frag)
  const int quad = lane >> 4;  // 0..3 -> k offset quad*8

  f32x4 acc[4][4] = {};

  for (int k0 = 0; k0 < Klen; k0 += 64) {
#pragma unroll
    for (int j = 0; j < 4; ++j) {
      gl2lds16(Ag + (size_t)j * 8 * lda + k0, Al + j * 8 * 64);
      gl2lds16(Bg + (size_t)j * 8 * ldb + k0, Bl + j * 8 * 64);
    }
    __syncthreads();  // compiler emits vmcnt(0) drain before barrier
#pragma unroll
    for (int kk = 0; kk < 64; kk += 32) {
      bf16x8 af[4], bfr[4];
#pragma unroll
      for (int i = 0; i < 4; ++i) {
        af[i] = *reinterpret_cast<const bf16x8*>(
            &As[(wm * 64 + i * 16 + lm) * 64 + kk + quad * 8]);
        bfr[i] = *reinterpret_cast<const bf16x8*>(
            &Bs[(wn * 64 + i * 16 + lm) * 64 + kk + quad * 8]);
      }
#pragma unroll
      for (int i = 0; i < 4; ++i)
#pragma unroll
        for (int j = 0; j < 4; ++j)
          acc[i][j] = __builtin_amdgcn_mfma_f32_16x16x32_bf16(
              af[i], bfr[j], acc[i][j], 0, 0, 0);
    }
    __syncthreads();
  }

  // epilogue: C/D layout col = lane&15 (n), row = quad*4 + reg (m)
  const int mBase = blockRow + wm * 64 + quad * 4;
  const int nBase = blockCol + wn * 64 + lm;
#pragma unroll
  for (int j = 0; j < 4; ++j) {
    const int n = nBase + j * 16;
    const float bv = bias ? bias[n] : 0.0f;
#pragma unroll
    for (int i = 0; i < 4; ++i) {
#pragma unroll
      for (int r = 0; r < 4; ++r) {
        const int m = mBase + i * 16 + r;
        float v = acc[i][j][r] * alpha + bv;
        if constexpr (sizeof(OutT) == 2)
          C[(size_t)m * ldc + n] = f32_to_bf16(v);
        else
          C[(size_t)m * ldc + n] = v;
      }
    }
  }
}

// ---------------------------------------------------------------------------
// reduce 4 fp32 split-K partials (each 4096x1024) -> bf16.  n4 = elems/4.
// ---------------------------------------------------------------------------
__global__ __launch_bounds__(256) void reduce4_bf16(
    const float* __restrict__ p, ushort_t* __restrict__ o, int n4) {
  int i = blockIdx.x * 256 + threadIdx.x;
  if (i >= n4) return;
  const float4* p4 = reinterpret_cast<const float4*>(p);
  float4 a = p4[i];
  float4 b = p4[i + 1048576];
  float4 c = p4[i + 2097152];
  float4 d = p4[i + 3145728];
  ushort4v u;
  u.x = f32_to_bf16(a.x + b.x + c.x + d.x);
  u.y = f32_to_bf16(a.y + b.y + c.y + d.y);
  u.z = f32_to_bf16(a.z + b.z + c.z + d.z);
  u.w = f32_to_bf16(a.w + b.w + c.w + d.w);
  reinterpret_cast<ushort4v*>(o)[i] = u;
}

// ---------------------------------------------------------------------------
// bf16 transpose: out[c][r] = in[r][c], per-batch slab of rows*cols.
// ---------------------------------------------------------------------------
__global__ __launch_bounds__(256) void transpose_bf16(
    const ushort_t* __restrict__ in, ushort_t* __restrict__ out, int rows,
    int cols) {
  __shared__ ushort_t tile[32][33];
  const size_t slab = (size_t)rows * cols;
  in += (size_t)blockIdx.z * slab;
  out += (size_t)blockIdx.z * slab;
  const int c0 = blockIdx.x * 32;
  const int r0 = blockIdx.y * 32;
  const int tx = threadIdx.x & 31;
  const int ty = threadIdx.x >> 5;  // 0..7
#pragma unroll
  for (int i = ty; i < 32; i += 8)
    tile[i][tx] = in[(size_t)(r0 + i) * cols + (c0 + tx)];
  __syncthreads();
#pragma unroll
  for (int i = ty; i < 32; i += 8)
    out[(size_t)(c0 + i) * rows + (r0 + tx)] = tile[tx][i];
}

// ---------------------------------------------------------------------------
// Row softmax over 4096 columns, fp32 in -> bf16 out.  grid (rows,1,1),
// block 256; 16 values per thread in registers.
// ---------------------------------------------------------------------------
__global__ __launch_bounds__(256) void softmax_rows(
    const float* __restrict__ Sc, ushort_t* __restrict__ P) {
  const size_t base = (size_t)blockIdx.x * 4096;
  const float* row = Sc + base;
  ushort_t* prow = P + base;
  const int tid = threadIdx.x;

  float4 v[4];
#pragma unroll
  for (int i = 0; i < 4; ++i)
    v[i] = reinterpret_cast<const float4*>(row)[i * 256 + tid];

  float mx = -3.0e38f;
#pragma unroll
  for (int i = 0; i < 4; ++i)
    mx = fmaxf(mx, fmaxf(fmaxf(v[i].x, v[i].y), fmaxf(v[i].z, v[i].w)));
#pragma unroll
  for (int o = 32; o > 0; o >>= 1) mx = fmaxf(mx, __shfl_xor(mx, o, 64));

  __shared__ float redmax[4];
  __shared__ float redsum[4];
  if ((tid & 63) == 0) redmax[tid >> 6] = mx;
  __syncthreads();
  mx = fmaxf(fmaxf(redmax[0], redmax[1]), fmaxf(redmax[2], redmax[3]));

  float sum = 0.0f;
#pragma unroll
  for (int i = 0; i < 4; ++i) {
    v[i].x = __expf(v[i].x - mx);
    v[i].y = __expf(v[i].y - mx);
    v[i].z = __expf(v[i].z - mx);
    v[i].w = __expf(v[i].w - mx);
    sum += v[i].x + v[i].y + v[i].z + v[i].w;
  }
#pragma unroll
  for (int o = 32; o > 0; o >>= 1) sum += __shfl_xor(sum, o, 64);
  if ((tid & 63) == 0) redsum[tid >> 6] = sum;
  __syncthreads();
  const float inv = 1.0f / (redsum[0] + redsum[1] + redsum[2] + redsum[3]);

#pragma unroll
  for (int i = 0; i < 4; ++i) {
    ushort4v o4;
    o4.x = f32_to_bf16(v[i].x * inv);
    o4.y = f32_to_bf16(v[i].y * inv);
    o4.z = f32_to_bf16(v[i].z * inv);
    o4.w = f32_to_bf16(v[i].w * inv);
    reinterpret_cast<ushort4v*>(prow)[i * 256 + tid] = o4;
  }
}

// ---------------------------------------------------------------------------
extern "C" void kernel_launch(void* const* d_in, const int* in_sizes, int n_in,
                              void* d_out, int out_size, void* d_ws,
                              size_t ws_size, hipStream_t stream) {
  (void)in_sizes; (void)n_in; (void)out_size; (void)ws_size;

  const float* x  = (const float*)d_in[0];
  const float* Wq = (const float*)d_in[1];
  const float* bq = (const float*)d_in[2];
  const float* Wk = (const float*)d_in[3];
  const float* bk = (const float*)d_in[4];
  const float* Wv = (const float*)d_in[5];
  const float* bv = (const float*)d_in[6];
  const float* Wo = (const float*)d_in[7];
  const float* bo = (const float*)d_in[8];
  float* out = (float*)d_out;

  constexpr int BATCH = 4, S = 4096, H = 1024;
  constexpr int M = BATCH * S;                   // 16384
  constexpr size_t SZ_X = (size_t)M * H;         // 16.8M elems (33.5 MB bf16)
  constexpr size_t SZ_W = (size_t)H * H;         // 1M elems   (2 MB bf16)
  constexpr float SCALE = 0.04419417382415922f;  // 1/sqrt(512)

  // --- workspace layout: 5 slabs + 4 weight buffers = ~176 MB total ---
  uint8_t* w = (uint8_t*)d_ws;
  ushort_t* xb  = (ushort_t*)w; w += SZ_X * 2;   // slab0: xb, later Ab
  ushort_t* wqb = (ushort_t*)w; w += SZ_W * 2;   // wq/wk/wv/wo contiguous
  ushort_t* wkb = (ushort_t*)w; w += SZ_W * 2;
  ushort_t* wvb = (ushort_t*)w; w += SZ_W * 2;
  ushort_t* wob = (ushort_t*)w; w += SZ_W * 2;
  ushort_t* Qb  = (ushort_t*)w; w += SZ_X * 2;   // slab1 (Q/K/V contiguous)
  ushort_t* Kb  = (ushort_t*)w; w += SZ_X * 2;   // slab2
  ushort_t* Vb  = (ushort_t*)w; w += SZ_X * 2;   // slab3: Vb, later Pb
  ushort_t* VTb = (ushort_t*)w; w += SZ_X * 2;   // slab4
  ushort_t* Ab = xb;   // x dead after QKV projection
  ushort_t* Pb = Vb;   // V dead after transpose
  float* Sc = out;     // d_out doubles as scores / split-K partials scratch;
                       // fully consumed before the final projection writes out
  (void)wkb; (void)wvb;

  const dim3 blk(256);
  const Bias4 nobias = {{nullptr, nullptr, nullptr, nullptr}};

  // fp32 -> bf16: x, then 4 weights in one grid.z=4 dispatch
  {
    Ptr4 px = {{x, nullptr, nullptr, nullptr}};
    cvt_f32_bf16<<<dim3((unsigned)(SZ_X / 4 / 256), 1, 1), blk, 0, stream>>>(
        px, xb, 0, (int)(SZ_X / 4));
    Ptr4 pw = {{Wq, Wk, Wv, Wo}};
    cvt_f32_bf16<<<dim3((unsigned)(SZ_W / 4 / 256), 1, 4), blk, 0, stream>>>(
        pw, wqb, SZ_W, (int)(SZ_W / 4));
  }

  // fused Q/K/V projections: one dispatch, grid.z picks weight/bias/output
  {
    Bias4 bqkv = {{bq, bk, bv, nullptr}};
    gemm_bt<ushort_t><<<dim3(H / 128, M / 128, 3), blk, 0, stream>>>(
        xb, wqb, bqkv, Qb, M, H, H, H, H, H, 1.0f, 0, SZ_W, SZ_X);
  }

  // V^T per batch: [S,H] -> [H,S]
  transpose_bf16<<<dim3(H / 32, S / 32, BATCH), blk, 0, stream>>>(Vb, VTb, S, H);

  // attention, one batch at a time (Sc / split-K partials reuse d_out)
  for (int b = 0; b < BATCH; ++b) {
    const ushort_t* Qp  = Qb  + (size_t)b * S * H;
    const ushort_t* Kp  = Kb  + (size_t)b * S * H;
    const ushort_t* VTp = VTb + (size_t)b * H * S;
    ushort_t* Ap = Ab + (size_t)b * S * H;
    // scores: [S,S] fp32 into d_out
    gemm_bt<float><<<dim3(S / 128, S / 128, 1), blk, 0, stream>>>(
        Qp, Kp, nobias, Sc, S, S, H, H, H, S, SCALE, 0, 0, 0);
    softmax_rows<<<dim3(S), blk, 0, stream>>>(Sc, Pb);
    // P @ V^T with split-K=4: z shifts the k-window by 1024 (zA=zB=1024),
    // each z writes its own fp32 partial (zC = S*H elems) into d_out
    gemm_bt<float><<<dim3(H / 128, S / 128, 4), blk, 0, stream>>>(
        Pb, VTp, nobias, (float*)out, S, H, 1024, S, S, H, 1.0f,
        1024, 1024, (size_t)S * H);
    reduce4_bf16<<<dim3((unsigned)(S * H / 4 / 256)), blk, 0, stream>>>(
        (const float*)out, Ap, S * H / 4);
  }

  // out = attn @ Wo^T + bo (fp32 out; overwrites the scratch in d_out)
  gemm_bt<float><<<dim3(H / 128, M / 128, 1), blk, 0, stream>>>(
      Ab, wob, {{bo, nullptr, nullptr, nullptr}}, out, M, H, H, H, H, H,
      1.0f, 0, 0, 0);
}

// Round 5
// 802.043 us; speedup vs baseline: 1.2289x; 1.1292x over previous
//
#include <hip/hip_runtime.h>
#include <cstdint>
#include <cstddef>

// ---------------------------------------------------------------------------
// WaveInterference: x -> Q,K,V (Linear) -> softmax(QK^T/sqrt(512)) V -> Wo
// B=4, S=4096, H=1024.  Heavy GEMMs in bf16 MFMA (fp32 accumulate).
//
// R4 -> R5: PV restructured.  Batches processed in pairs; P kept for two
// batches at once (P0->Vb, P1->xb; pair1: P2->Vb, P3->Kb — all dead slabs),
// one PV dispatch per pair with z=(batch,khalf), Klen=2048 (32 K-iters vs
// 16), 1024 blocks.  The 4 fp32 partials fit d_out EXACTLY (4 x 16.8 MB).
// reduce2 packs A slabs contiguously into xb.  Partial traffic halved
// (536 -> 268 MB).  Per-z alpha folds 1/sqrt(512) into the Q projection.
// ---------------------------------------------------------------------------

typedef unsigned short ushort_t;
typedef __bf16 bf16x8 __attribute__((ext_vector_type(8)));
typedef float f32x4 __attribute__((ext_vector_type(4)));
typedef unsigned short ushort4v __attribute__((ext_vector_type(4)));

struct Ptr4 { const float* p[4]; };      // cvt sources
struct BPtr4 { const ushort_t* p[4]; };  // per-z A/B operand tables
struct Bias4 { const float* p[4]; };
struct Alpha4 { float a[4]; };

__device__ __forceinline__ ushort_t f32_to_bf16(float f) {
  union { float f; unsigned int u; } x;
  x.f = f;
  unsigned int r = x.u + 0x7FFFu + ((x.u >> 16) & 1u);  // round-to-nearest-even
  return (ushort_t)(r >> 16);
}

// async 16B global -> LDS (LDS dst must be wave-uniform base + lane*16)
__device__ __forceinline__ void gl2lds16(const ushort_t* g, ushort_t* l) {
  __builtin_amdgcn_global_load_lds(
      (__attribute__((address_space(1))) void*)(g),
      (__attribute__((address_space(3))) void*)(l),
      16, 0, 0);
}

// ---------------------------------------------------------------------------
// fp32 -> bf16, 4 elems/thread; grid.z selects among 4 (src, dst-slab) pairs
// ---------------------------------------------------------------------------
__global__ __launch_bounds__(256) void cvt_f32_bf16(
    Ptr4 srcs, ushort_t* __restrict__ out0, size_t zstride, int n4) {
  int i = blockIdx.x * 256 + threadIdx.x;
  if (i >= n4) return;
  const float* in = srcs.p[blockIdx.z & 3];
  ushort_t* out = out0 + zstride * blockIdx.z;
  float4 f = reinterpret_cast<const float4*>(in)[i];
  ushort4v o;
  o.x = f32_to_bf16(f.x);
  o.y = f32_to_bf16(f.y);
  o.z = f32_to_bf16(f.z);
  o.w = f32_to_bf16(f.w);
  reinterpret_cast<ushort4v*>(out)[i] = o;
}

// ---------------------------------------------------------------------------
// C[m,n] = alpha_z * sum_{k<Klen} A_z[m,k]*B_z[n,k] (+ bias_z[n]).  A,B bf16
// row-major with leading dims lda/ldb; C leading dim ldc, advanced z*zC.
// Per-z operand tables enable fused QKV (z=proj) and paired split-K PV
// (z=(batch,khalf)).  128x128 tile, BK=64, 4 waves (2x2), 16x16x32 bf16
// MFMA, global_load_lds width-16 staging.  Requires gridDim.y % 8 == 0.
// ---------------------------------------------------------------------------
template <typename OutT>
__global__ __launch_bounds__(256, 3) void gemm_bt(
    BPtr4 a4, BPtr4 b4, Bias4 bz, Alpha4 al, OutT* __restrict__ C,
    int Klen, int lda, int ldb, int ldc, size_t zC) {
  __shared__ __align__(16) ushort_t As[128 * 64];
  __shared__ __align__(16) ushort_t Bs[128 * 64];

  const int z = blockIdx.z & 3;
  const ushort_t* __restrict__ A = a4.p[z];
  const ushort_t* __restrict__ B = b4.p[z];
  const float* bias = bz.p[z];
  const float alpha = al.a[z];
  C += (size_t)blockIdx.z * zC;

  // --- XCD band swizzle.  HW: xcd = linear_block_id % 8.  Each XCD owns a
  // horizontal band of gridDim.y/8 block-rows, walked column-major so the A
  // band stays L2-resident while B streams once per XCD. ---
  const int flat = blockIdx.x + gridDim.x * blockIdx.y;
  const int bandH = gridDim.y >> 3;
  const int xcd = flat & 7;
  const int slot = flat >> 3;
  const int bxs = slot / bandH;
  const int bys = xcd * bandH + (slot - bxs * bandH);
  const int blockRow = bys * 128;
  const int blockCol = bxs * 128;

  const int tid = threadIdx.x;
  const int lane = tid & 63;
  const int wave = tid >> 6;
  const int wm = wave >> 1;  // wave row (0..1), 64 rows each
  const int wn = wave & 1;   // wave col (0..1), 64 cols each

  // staging: each wave covers 32 rows of the 128x64 tile in 4 issues of 8 rows
  const int srow = wave * 32 + (lane >> 3);
  const int scol = (lane & 7) * 8;  // bf16 elems in the 64-wide K slab
  const ushort_t* Ag = A + (size_t)(blockRow + srow) * lda + scol;
  const ushort_t* Bg = B + (size_t)(blockCol + srow) * ldb + scol;
  ushort_t* Al = &As[srow * 64 + scol];  // = As + (wavebase + lane*16B)
  ushort_t* Bl = &Bs[srow * 64 + scol];

  const int lm = lane & 15;    // m (A frag) / n (B frag)
  const int quad = lane >> 4;  // 0..3 -> k offset quad*8

  f32x4 acc[4][4] = {};

  for (int k0 = 0; k0 < Klen; k0 += 64) {
#pragma unroll
    for (int j = 0; j < 4; ++j) {
      gl2lds16(Ag + (size_t)j * 8 * lda + k0, Al + j * 8 * 64);
      gl2lds16(Bg + (size_t)j * 8 * ldb + k0, Bl + j * 8 * 64);
    }
    __syncthreads();  // compiler emits vmcnt(0) drain before barrier
#pragma unroll
    for (int kk = 0; kk < 64; kk += 32) {
      bf16x8 af[4], bfr[4];
#pragma unroll
      for (int i = 0; i < 4; ++i) {
        af[i] = *reinterpret_cast<const bf16x8*>(
            &As[(wm * 64 + i * 16 + lm) * 64 + kk + quad * 8]);
        bfr[i] = *reinterpret_cast<const bf16x8*>(
            &Bs[(wn * 64 + i * 16 + lm) * 64 + kk + quad * 8]);
      }
#pragma unroll
      for (int i = 0; i < 4; ++i)
#pragma unroll
        for (int j = 0; j < 4; ++j)
          acc[i][j] = __builtin_amdgcn_mfma_f32_16x16x32_bf16(
              af[i], bfr[j], acc[i][j], 0, 0, 0);
    }
    __syncthreads();
  }

  // epilogue: C/D layout col = lane&15 (n), row = quad*4 + reg (m)
  const int mBase = blockRow + wm * 64 + quad * 4;
  const int nBase = blockCol + wn * 64 + lm;
#pragma unroll
  for (int j = 0; j < 4; ++j) {
    const int n = nBase + j * 16;
    const float bv = bias ? bias[n] : 0.0f;
#pragma unroll
    for (int i = 0; i < 4; ++i) {
#pragma unroll
      for (int r = 0; r < 4; ++r) {
        const int m = mBase + i * 16 + r;
        float v = acc[i][j][r] * alpha + bv;
        if constexpr (sizeof(OutT) == 2)
          C[(size_t)m * ldc + n] = f32_to_bf16(v);
        else
          C[(size_t)m * ldc + n] = v;
      }
    }
  }
}

// ---------------------------------------------------------------------------
// reduce pairs of fp32 split-K partials -> bf16.  Partials D[0..3] each
// npb4*4 elems; out[b2] = D[2*b2] + D[2*b2+1], b2 in {0,1}.
// grid.x covers 2*npb4 indices.
// ---------------------------------------------------------------------------
__global__ __launch_bounds__(256) void reduce2_bf16(
    const float* __restrict__ D, ushort_t* __restrict__ o, int npb4) {
  int i = blockIdx.x * 256 + threadIdx.x;
  if (i >= 2 * npb4) return;
  const int b2 = i / npb4;
  const int j = i - b2 * npb4;
  const float4* p4 = reinterpret_cast<const float4*>(D);
  float4 a = p4[(size_t)(2 * b2) * npb4 + j];
  float4 b = p4[(size_t)(2 * b2 + 1) * npb4 + j];
  ushort4v u;
  u.x = f32_to_bf16(a.x + b.x);
  u.y = f32_to_bf16(a.y + b.y);
  u.z = f32_to_bf16(a.z + b.z);
  u.w = f32_to_bf16(a.w + b.w);
  reinterpret_cast<ushort4v*>(o)[(size_t)b2 * npb4 + j] = u;
}

// ---------------------------------------------------------------------------
// bf16 transpose: out[c][r] = in[r][c], per-batch slab of rows*cols.
// ---------------------------------------------------------------------------
__global__ __launch_bounds__(256) void transpose_bf16(
    const ushort_t* __restrict__ in, ushort_t* __restrict__ out, int rows,
    int cols) {
  __shared__ ushort_t tile[32][33];
  const size_t slab = (size_t)rows * cols;
  in += (size_t)blockIdx.z * slab;
  out += (size_t)blockIdx.z * slab;
  const int c0 = blockIdx.x * 32;
  const int r0 = blockIdx.y * 32;
  const int tx = threadIdx.x & 31;
  const int ty = threadIdx.x >> 5;  // 0..7
#pragma unroll
  for (int i = ty; i < 32; i += 8)
    tile[i][tx] = in[(size_t)(r0 + i) * cols + (c0 + tx)];
  __syncthreads();
#pragma unroll
  for (int i = ty; i < 32; i += 8)
    out[(size_t)(c0 + i) * rows + (r0 + tx)] = tile[tx][i];
}

// ---------------------------------------------------------------------------
// Row softmax over 4096 columns, fp32 in -> bf16 out.  grid (rows,1,1),
// block 256; 16 values per thread in registers.
// ---------------------------------------------------------------------------
__global__ __launch_bounds__(256) void softmax_rows(
    const float* __restrict__ Sc, ushort_t* __restrict__ P) {
  const size_t base = (size_t)blockIdx.x * 4096;
  const float* row = Sc + base;
  ushort_t* prow = P + base;
  const int tid = threadIdx.x;

  float4 v[4];
#pragma unroll
  for (int i = 0; i < 4; ++i)
    v[i] = reinterpret_cast<const float4*>(row)[i * 256 + tid];

  float mx = -3.0e38f;
#pragma unroll
  for (int i = 0; i < 4; ++i)
    mx = fmaxf(mx, fmaxf(fmaxf(v[i].x, v[i].y), fmaxf(v[i].z, v[i].w)));
#pragma unroll
  for (int o = 32; o > 0; o >>= 1) mx = fmaxf(mx, __shfl_xor(mx, o, 64));

  __shared__ float redmax[4];
  __shared__ float redsum[4];
  if ((tid & 63) == 0) redmax[tid >> 6] = mx;
  __syncthreads();
  mx = fmaxf(fmaxf(redmax[0], redmax[1]), fmaxf(redmax[2], redmax[3]));

  float sum = 0.0f;
#pragma unroll
  for (int i = 0; i < 4; ++i) {
    v[i].x = __expf(v[i].x - mx);
    v[i].y = __expf(v[i].y - mx);
    v[i].z = __expf(v[i].z - mx);
    v[i].w = __expf(v[i].w - mx);
    sum += v[i].x + v[i].y + v[i].z + v[i].w;
  }
#pragma unroll
  for (int o = 32; o > 0; o >>= 1) sum += __shfl_xor(sum, o, 64);
  if ((tid & 63) == 0) redsum[tid >> 6] = sum;
  __syncthreads();
  const float inv = 1.0f / (redsum[0] + redsum[1] + redsum[2] + redsum[3]);

#pragma unroll
  for (int i = 0; i < 4; ++i) {
    ushort4v o4;
    o4.x = f32_to_bf16(v[i].x * inv);
    o4.y = f32_to_bf16(v[i].y * inv);
    o4.z = f32_to_bf16(v[i].z * inv);
    o4.w = f32_to_bf16(v[i].w * inv);
    reinterpret_cast<ushort4v*>(prow)[i * 256 + tid] = o4;
  }
}

// ---------------------------------------------------------------------------
extern "C" void kernel_launch(void* const* d_in, const int* in_sizes, int n_in,
                              void* d_out, int out_size, void* d_ws,
                              size_t ws_size, hipStream_t stream) {
  (void)in_sizes; (void)n_in; (void)out_size; (void)ws_size;

  const float* x  = (const float*)d_in[0];
  const float* Wq = (const float*)d_in[1];
  const float* bq = (const float*)d_in[2];
  const float* Wk = (const float*)d_in[3];
  const float* bk = (const float*)d_in[4];
  const float* Wv = (const float*)d_in[5];
  const float* bv = (const float*)d_in[6];
  const float* Wo = (const float*)d_in[7];
  const float* bo = (const float*)d_in[8];
  float* out = (float*)d_out;

  constexpr int BATCH = 4, S = 4096, H = 1024;
  constexpr int M = BATCH * S;                   // 16384
  constexpr size_t SZ_X = (size_t)M * H;         // 16.8M elems (33.5 MB bf16)
  constexpr size_t SZ_W = (size_t)H * H;         // 1M elems   (2 MB bf16)
  constexpr size_t SH = (size_t)S * H;           // 4.2M elems per batch
  constexpr float SCALE = 0.04419417382415922f;  // 1/sqrt(512)

  // --- workspace layout: 5 slabs + 4 weight buffers = ~176 MB total ---
  uint8_t* w = (uint8_t*)d_ws;
  ushort_t* xb  = (ushort_t*)w; w += SZ_X * 2;   // slab0: xb -> P1 -> A0..A3
  ushort_t* wqb = (ushort_t*)w; w += SZ_W * 2;
  ushort_t* wkb = (ushort_t*)w; w += SZ_W * 2;
  ushort_t* wvb = (ushort_t*)w; w += SZ_W * 2;
  ushort_t* wob = (ushort_t*)w; w += SZ_W * 2;
  ushort_t* Qb  = (ushort_t*)w; w += SZ_X * 2;   // slab1
  ushort_t* Kb  = (ushort_t*)w; w += SZ_X * 2;   // slab2: Kb -> P3
  ushort_t* Vb  = (ushort_t*)w; w += SZ_X * 2;   // slab3: Vb -> P0 / P2
  ushort_t* VTb = (ushort_t*)w; w += SZ_X * 2;   // slab4
  float* D = out;  // scores scratch AND 4 x 16.8 MB split-K partials (exact)

  const dim3 blk(256);
  const Bias4 nobias = {{nullptr, nullptr, nullptr, nullptr}};
  const Alpha4 ones = {{1.0f, 1.0f, 1.0f, 1.0f}};

  // fp32 -> bf16: x, then 4 weights in one grid.z=4 dispatch
  {
    Ptr4 px = {{x, nullptr, nullptr, nullptr}};
    cvt_f32_bf16<<<dim3((unsigned)(SZ_X / 4 / 256), 1, 1), blk, 0, stream>>>(
        px, xb, 0, (int)(SZ_X / 4));
    Ptr4 pw = {{Wq, Wk, Wv, Wo}};
    cvt_f32_bf16<<<dim3((unsigned)(SZ_W / 4 / 256), 1, 4), blk, 0, stream>>>(
        pw, wqb, SZ_W, (int)(SZ_W / 4));
  }

  // fused Q/K/V projections; 1/sqrt(512) folded into Q (bq is zeros)
  {
    BPtr4 a4 = {{xb, xb, xb, xb}};
    BPtr4 b4 = {{wqb, wkb, wvb, wqb}};
    Bias4 bqkv = {{bq, bk, bv, nullptr}};
    Alpha4 al = {{SCALE, 1.0f, 1.0f, 1.0f}};
    gemm_bt<ushort_t><<<dim3(H / 128, M / 128, 3), blk, 0, stream>>>(
        a4, b4, bqkv, al, Qb, H, H, H, H, SZ_X);
  }

  // V^T per batch: [S,H] -> [H,S]
  transpose_bf16<<<dim3(H / 32, S / 32, BATCH), blk, 0, stream>>>(Vb, VTb, S, H);

  // attention in batch pairs
  for (int p = 0; p < 2; ++p) {
    // P destinations: pair0 -> {Vb, xb} (x dead); pair1 -> {Vb, Kb} (K dead
    // after the last scores gemm of the pair)
    ushort_t* Pdst[2] = {Vb, (p == 0) ? xb : Kb};
    for (int b2 = 0; b2 < 2; ++b2) {
      const int b = 2 * p + b2;
      const ushort_t* Qp = Qb + (size_t)b * SH;
      const ushort_t* Kp = Kb + (size_t)b * SH;
      BPtr4 a4 = {{Qp, Qp, Qp, Qp}};
      BPtr4 b4 = {{Kp, Kp, Kp, Kp}};
      gemm_bt<float><<<dim3(S / 128, S / 128, 1), blk, 0, stream>>>(
          a4, b4, nobias, ones, D, H, H, H, S, 0);
      softmax_rows<<<dim3(S), blk, 0, stream>>>(D, Pdst[b2]);
    }
    // paired PV, split-K=2: z = b2*2 + khalf, Klen=2048, 1024 blocks.
    // fp32 partials fill d_out exactly (4 x S*H elems).
    {
      const ushort_t* VT0 = VTb + (size_t)(2 * p) * SH;
      const ushort_t* VT1 = VTb + (size_t)(2 * p + 1) * SH;
      BPtr4 a4 = {{Pdst[0], Pdst[0] + 2048, Pdst[1], Pdst[1] + 2048}};
      BPtr4 b4 = {{VT0, VT0 + 2048, VT1, VT1 + 2048}};
      gemm_bt<float><<<dim3(H / 128, S / 128, 4), blk, 0, stream>>>(
          a4, b4, nobias, ones, D, 2048, S, S, H, SH);
    }
    // A(2p), A(2p+1) packed contiguously into xb (P1 dead by now)
    reduce2_bf16<<<dim3((unsigned)(2 * SH / 4 / 256)), blk, 0, stream>>>(
        D, xb + (size_t)(2 * p) * SH, (int)(SH / 4));
  }

  // out = attn @ Wo^T + bo (fp32 out; partials in d_out already consumed)
  {
    BPtr4 a4 = {{xb, xb, xb, xb}};
    BPtr4 b4 = {{wob, wob, wob, wob}};
    Bias4 bb = {{bo, nullptr, nullptr, nullptr}};
    gemm_bt<float><<<dim3(H / 128, M / 128, 1), blk, 0, stream>>>(
        a4, b4, bb, ones, out, H, H, H, H, 0);
  }
}

// Round 6
// 761.144 us; speedup vs baseline: 1.2950x; 1.0537x over previous
//
#include <hip/hip_runtime.h>
#include <cstdint>
#include <cstddef>

// ---------------------------------------------------------------------------
// WaveInterference: x -> Q,K,V (Linear) -> softmax(QK^T/sqrt(512)) V -> Wo
// B=4, S=4096, H=1024.  Heavy GEMMs in bf16 MFMA (fp32 accumulate).
//
// R5 -> R6: split-K + reduce2 eliminated (was 536 MB fp32 partial traffic,
// ~110 us).  Batch pairs processed {2,3} then {0,1}; after batch b's scores
// gemm its Q slot is dead, so PV (Klen=4096, z=2, 512 blocks, bf16 out)
// writes A_b straight into Qb + b*SH.  Final projection reads A = Qb.
// d_out is now scores-only scratch.
// ---------------------------------------------------------------------------

typedef unsigned short ushort_t;
typedef __bf16 bf16x8 __attribute__((ext_vector_type(8)));
typedef float f32x4 __attribute__((ext_vector_type(4)));
typedef unsigned short ushort4v __attribute__((ext_vector_type(4)));

struct Ptr4 { const float* p[4]; };      // cvt sources
struct BPtr4 { const ushort_t* p[4]; };  // per-z A/B operand tables
struct Bias4 { const float* p[4]; };
struct Alpha4 { float a[4]; };

__device__ __forceinline__ ushort_t f32_to_bf16(float f) {
  union { float f; unsigned int u; } x;
  x.f = f;
  unsigned int r = x.u + 0x7FFFu + ((x.u >> 16) & 1u);  // round-to-nearest-even
  return (ushort_t)(r >> 16);
}

// async 16B global -> LDS (LDS dst must be wave-uniform base + lane*16)
__device__ __forceinline__ void gl2lds16(const ushort_t* g, ushort_t* l) {
  __builtin_amdgcn_global_load_lds(
      (__attribute__((address_space(1))) void*)(g),
      (__attribute__((address_space(3))) void*)(l),
      16, 0, 0);
}

// ---------------------------------------------------------------------------
// fp32 -> bf16, 4 elems/thread; grid.z selects among 4 (src, dst-slab) pairs
// ---------------------------------------------------------------------------
__global__ __launch_bounds__(256) void cvt_f32_bf16(
    Ptr4 srcs, ushort_t* __restrict__ out0, size_t zstride, int n4) {
  int i = blockIdx.x * 256 + threadIdx.x;
  if (i >= n4) return;
  const float* in = srcs.p[blockIdx.z & 3];
  ushort_t* out = out0 + zstride * blockIdx.z;
  float4 f = reinterpret_cast<const float4*>(in)[i];
  ushort4v o;
  o.x = f32_to_bf16(f.x);
  o.y = f32_to_bf16(f.y);
  o.z = f32_to_bf16(f.z);
  o.w = f32_to_bf16(f.w);
  reinterpret_cast<ushort4v*>(out)[i] = o;
}

// ---------------------------------------------------------------------------
// C[m,n] = alpha_z * sum_{k<Klen} A_z[m,k]*B_z[n,k] (+ bias_z[n]).  A,B bf16
// row-major with leading dims lda/ldb; C leading dim ldc, advanced z*zC.
// Per-z operand tables enable fused QKV (z=proj) and paired PV (z=batch).
// 128x128 tile, BK=64, 4 waves (2x2), 16x16x32 bf16 MFMA, global_load_lds
// width-16 staging, XCD band swizzle.  Requires gridDim.y % 8 == 0.
// ---------------------------------------------------------------------------
template <typename OutT>
__global__ __launch_bounds__(256, 3) void gemm_bt(
    BPtr4 a4, BPtr4 b4, Bias4 bz, Alpha4 al, OutT* __restrict__ C,
    int Klen, int lda, int ldb, int ldc, size_t zC) {
  __shared__ __align__(16) ushort_t As[128 * 64];
  __shared__ __align__(16) ushort_t Bs[128 * 64];

  const int z = blockIdx.z & 3;
  const ushort_t* __restrict__ A = a4.p[z];
  const ushort_t* __restrict__ B = b4.p[z];
  const float* bias = bz.p[z];
  const float alpha = al.a[z];
  C += (size_t)blockIdx.z * zC;

  // --- XCD band swizzle.  HW: xcd = linear_block_id % 8.  Each XCD owns a
  // horizontal band of gridDim.y/8 block-rows, walked column-major so the A
  // band stays L2-resident while B streams once per XCD. ---
  const int flat = blockIdx.x + gridDim.x * blockIdx.y;
  const int bandH = gridDim.y >> 3;
  const int xcd = flat & 7;
  const int slot = flat >> 3;
  const int bxs = slot / bandH;
  const int bys = xcd * bandH + (slot - bxs * bandH);
  const int blockRow = bys * 128;
  const int blockCol = bxs * 128;

  const int tid = threadIdx.x;
  const int lane = tid & 63;
  const int wave = tid >> 6;
  const int wm = wave >> 1;  // wave row (0..1), 64 rows each
  const int wn = wave & 1;   // wave col (0..1), 64 cols each

  // staging: each wave covers 32 rows of the 128x64 tile in 4 issues of 8 rows
  const int srow = wave * 32 + (lane >> 3);
  const int scol = (lane & 7) * 8;  // bf16 elems in the 64-wide K slab
  const ushort_t* Ag = A + (size_t)(blockRow + srow) * lda + scol;
  const ushort_t* Bg = B + (size_t)(blockCol + srow) * ldb + scol;
  ushort_t* Al = &As[srow * 64 + scol];  // = As + (wavebase + lane*16B)
  ushort_t* Bl = &Bs[srow * 64 + scol];

  const int lm = lane & 15;    // m (A frag) / n (B frag)
  const int quad = lane >> 4;  // 0..3 -> k offset quad*8

  f32x4 acc[4][4] = {};

  for (int k0 = 0; k0 < Klen; k0 += 64) {
#pragma unroll
    for (int j = 0; j < 4; ++j) {
      gl2lds16(Ag + (size_t)j * 8 * lda + k0, Al + j * 8 * 64);
      gl2lds16(Bg + (size_t)j * 8 * ldb + k0, Bl + j * 8 * 64);
    }
    __syncthreads();  // compiler emits vmcnt(0) drain before barrier
#pragma unroll
    for (int kk = 0; kk < 64; kk += 32) {
      bf16x8 af[4], bfr[4];
#pragma unroll
      for (int i = 0; i < 4; ++i) {
        af[i] = *reinterpret_cast<const bf16x8*>(
            &As[(wm * 64 + i * 16 + lm) * 64 + kk + quad * 8]);
        bfr[i] = *reinterpret_cast<const bf16x8*>(
            &Bs[(wn * 64 + i * 16 + lm) * 64 + kk + quad * 8]);
      }
#pragma unroll
      for (int i = 0; i < 4; ++i)
#pragma unroll
        for (int j = 0; j < 4; ++j)
          acc[i][j] = __builtin_amdgcn_mfma_f32_16x16x32_bf16(
              af[i], bfr[j], acc[i][j], 0, 0, 0);
    }
    __syncthreads();
  }

  // epilogue: C/D layout col = lane&15 (n), row = quad*4 + reg (m)
  const int mBase = blockRow + wm * 64 + quad * 4;
  const int nBase = blockCol + wn * 64 + lm;
#pragma unroll
  for (int j = 0; j < 4; ++j) {
    const int n = nBase + j * 16;
    const float bv = bias ? bias[n] : 0.0f;
#pragma unroll
    for (int i = 0; i < 4; ++i) {
#pragma unroll
      for (int r = 0; r < 4; ++r) {
        const int m = mBase + i * 16 + r;
        float v = acc[i][j][r] * alpha + bv;
        if constexpr (sizeof(OutT) == 2)
          C[(size_t)m * ldc + n] = f32_to_bf16(v);
        else
          C[(size_t)m * ldc + n] = v;
      }
    }
  }
}

// ---------------------------------------------------------------------------
// bf16 transpose: out[c][r] = in[r][c], per-batch slab of rows*cols.
// ---------------------------------------------------------------------------
__global__ __launch_bounds__(256) void transpose_bf16(
    const ushort_t* __restrict__ in, ushort_t* __restrict__ out, int rows,
    int cols) {
  __shared__ ushort_t tile[32][33];
  const size_t slab = (size_t)rows * cols;
  in += (size_t)blockIdx.z * slab;
  out += (size_t)blockIdx.z * slab;
  const int c0 = blockIdx.x * 32;
  const int r0 = blockIdx.y * 32;
  const int tx = threadIdx.x & 31;
  const int ty = threadIdx.x >> 5;  // 0..7
#pragma unroll
  for (int i = ty; i < 32; i += 8)
    tile[i][tx] = in[(size_t)(r0 + i) * cols + (c0 + tx)];
  __syncthreads();
#pragma unroll
  for (int i = ty; i < 32; i += 8)
    out[(size_t)(c0 + i) * rows + (r0 + tx)] = tile[tx][i];
}

// ---------------------------------------------------------------------------
// Row softmax over 4096 columns, fp32 in -> bf16 out.  grid (rows,1,1),
// block 256; 16 values per thread in registers.
// ---------------------------------------------------------------------------
__global__ __launch_bounds__(256) void softmax_rows(
    const float* __restrict__ Sc, ushort_t* __restrict__ P) {
  const size_t base = (size_t)blockIdx.x * 4096;
  const float* row = Sc + base;
  ushort_t* prow = P + base;
  const int tid = threadIdx.x;

  float4 v[4];
#pragma unroll
  for (int i = 0; i < 4; ++i)
    v[i] = reinterpret_cast<const float4*>(row)[i * 256 + tid];

  float mx = -3.0e38f;
#pragma unroll
  for (int i = 0; i < 4; ++i)
    mx = fmaxf(mx, fmaxf(fmaxf(v[i].x, v[i].y), fmaxf(v[i].z, v[i].w)));
#pragma unroll
  for (int o = 32; o > 0; o >>= 1) mx = fmaxf(mx, __shfl_xor(mx, o, 64));

  __shared__ float redmax[4];
  __shared__ float redsum[4];
  if ((tid & 63) == 0) redmax[tid >> 6] = mx;
  __syncthreads();
  mx = fmaxf(fmaxf(redmax[0], redmax[1]), fmaxf(redmax[2], redmax[3]));

  float sum = 0.0f;
#pragma unroll
  for (int i = 0; i < 4; ++i) {
    v[i].x = __expf(v[i].x - mx);
    v[i].y = __expf(v[i].y - mx);
    v[i].z = __expf(v[i].z - mx);
    v[i].w = __expf(v[i].w - mx);
    sum += v[i].x + v[i].y + v[i].z + v[i].w;
  }
#pragma unroll
  for (int o = 32; o > 0; o >>= 1) sum += __shfl_xor(sum, o, 64);
  if ((tid & 63) == 0) redsum[tid >> 6] = sum;
  __syncthreads();
  const float inv = 1.0f / (redsum[0] + redsum[1] + redsum[2] + redsum[3]);

#pragma unroll
  for (int i = 0; i < 4; ++i) {
    ushort4v o4;
    o4.x = f32_to_bf16(v[i].x * inv);
    o4.y = f32_to_bf16(v[i].y * inv);
    o4.z = f32_to_bf16(v[i].z * inv);
    o4.w = f32_to_bf16(v[i].w * inv);
    reinterpret_cast<ushort4v*>(prow)[i * 256 + tid] = o4;
  }
}

// ---------------------------------------------------------------------------
extern "C" void kernel_launch(void* const* d_in, const int* in_sizes, int n_in,
                              void* d_out, int out_size, void* d_ws,
                              size_t ws_size, hipStream_t stream) {
  (void)in_sizes; (void)n_in; (void)out_size; (void)ws_size;

  const float* x  = (const float*)d_in[0];
  const float* Wq = (const float*)d_in[1];
  const float* bq = (const float*)d_in[2];
  const float* Wk = (const float*)d_in[3];
  const float* bk = (const float*)d_in[4];
  const float* Wv = (const float*)d_in[5];
  const float* bv = (const float*)d_in[6];
  const float* Wo = (const float*)d_in[7];
  const float* bo = (const float*)d_in[8];
  float* out = (float*)d_out;

  constexpr int BATCH = 4, S = 4096, H = 1024;
  constexpr int M = BATCH * S;                   // 16384
  constexpr size_t SZ_X = (size_t)M * H;         // 16.8M elems (33.5 MB bf16)
  constexpr size_t SZ_W = (size_t)H * H;         // 1M elems   (2 MB bf16)
  constexpr size_t SH = (size_t)S * H;           // 4.2M elems per batch
  constexpr float SCALE = 0.04419417382415922f;  // 1/sqrt(512)

  // --- workspace layout: 5 slabs + 4 weight buffers = ~176 MB total ---
  uint8_t* w = (uint8_t*)d_ws;
  ushort_t* xb  = (ushort_t*)w; w += SZ_X * 2;   // slab0: xb -> P3 / P1
  ushort_t* wqb = (ushort_t*)w; w += SZ_W * 2;
  ushort_t* wkb = (ushort_t*)w; w += SZ_W * 2;
  ushort_t* wvb = (ushort_t*)w; w += SZ_W * 2;
  ushort_t* wob = (ushort_t*)w; w += SZ_W * 2;
  ushort_t* Qb  = (ushort_t*)w; w += SZ_X * 2;   // slab1: Q -> A (per-slot)
  ushort_t* Kb  = (ushort_t*)w; w += SZ_X * 2;   // slab2
  ushort_t* Vb  = (ushort_t*)w; w += SZ_X * 2;   // slab3: Vb -> P2 / P0
  ushort_t* VTb = (ushort_t*)w; w += SZ_X * 2;   // slab4
  float* D = out;  // scores scratch only (67 MB, exact fit)

  const dim3 blk(256);
  const Bias4 nobias = {{nullptr, nullptr, nullptr, nullptr}};
  const Alpha4 ones = {{1.0f, 1.0f, 1.0f, 1.0f}};

  // fp32 -> bf16: x, then 4 weights in one grid.z=4 dispatch
  {
    Ptr4 px = {{x, nullptr, nullptr, nullptr}};
    cvt_f32_bf16<<<dim3((unsigned)(SZ_X / 4 / 256), 1, 1), blk, 0, stream>>>(
        px, xb, 0, (int)(SZ_X / 4));
    Ptr4 pw = {{Wq, Wk, Wv, Wo}};
    cvt_f32_bf16<<<dim3((unsigned)(SZ_W / 4 / 256), 1, 4), blk, 0, stream>>>(
        pw, wqb, SZ_W, (int)(SZ_W / 4));
  }

  // fused Q/K/V projections; 1/sqrt(512) folded into Q (bq is zeros)
  {
    BPtr4 a4 = {{xb, xb, xb, xb}};
    BPtr4 b4 = {{wqb, wkb, wvb, wqb}};
    Bias4 bqkv = {{bq, bk, bv, nullptr}};
    Alpha4 al = {{SCALE, 1.0f, 1.0f, 1.0f}};
    gemm_bt<ushort_t><<<dim3(H / 128, M / 128, 3), blk, 0, stream>>>(
        a4, b4, bqkv, al, Qb, H, H, H, H, SZ_X);
  }

  // V^T per batch: [S,H] -> [H,S]
  transpose_bf16<<<dim3(H / 32, S / 32, BATCH), blk, 0, stream>>>(Vb, VTb, S, H);

  // attention in batch pairs, {2,3} first so A_b can reuse dead Q slots
  for (int p = 1; p >= 0; --p) {
    ushort_t* Pdst[2] = {Vb, xb};  // Vb dead after VT; xb dead after QKV
    for (int b2 = 0; b2 < 2; ++b2) {
      const int b = 2 * p + b2;
      const ushort_t* Qp = Qb + (size_t)b * SH;
      const ushort_t* Kp = Kb + (size_t)b * SH;
      BPtr4 a4 = {{Qp, Qp, Qp, Qp}};
      BPtr4 b4 = {{Kp, Kp, Kp, Kp}};
      gemm_bt<float><<<dim3(S / 128, S / 128, 1), blk, 0, stream>>>(
          a4, b4, nobias, ones, D, H, H, H, S, 0);
      softmax_rows<<<dim3(S), blk, 0, stream>>>(D, Pdst[b2]);
    }
    // paired PV: z = batch-in-pair, Klen=4096, 512 blocks, bf16 A written
    // into the pair's dead Q slots (Qb + (2p+z)*SH)
    {
      const ushort_t* VT0 = VTb + (size_t)(2 * p) * SH;
      const ushort_t* VT1 = VTb + (size_t)(2 * p + 1) * SH;
      BPtr4 a4 = {{Pdst[0], Pdst[1], Pdst[0], Pdst[1]}};
      BPtr4 b4 = {{VT0, VT1, VT0, VT1}};
      gemm_bt<ushort_t><<<dim3(H / 128, S / 128, 2), blk, 0, stream>>>(
          a4, b4, nobias, ones, Qb + (size_t)(2 * p) * SH, S, S, S, H, SH);
    }
  }

  // out = attn @ Wo^T + bo (fp32 out; A = Qb, packed contiguously)
  {
    BPtr4 a4 = {{Qb, Qb, Qb, Qb}};
    BPtr4 b4 = {{wob, wob, wob, wob}};
    Bias4 bb = {{bo, nullptr, nullptr, nullptr}};
    gemm_bt<float><<<dim3(H / 128, M / 128, 1), blk, 0, stream>>>(
        a4, b4, bb, ones, out, H, H, H, H, 0);
  }
}